// Round 9
// baseline (157.341 us; speedup 1.0000x reference)
//
#include <hip/hip_runtime.h>

// Problem constants
#define BATCH 1024
#define SEQ   336
#define CCH   64
#define ORD   168
#define TT    96
#define OFF   168
#define KP    192            // K padded to 12 kt-chunks of 16

typedef __attribute__((ext_vector_type(8)))  short  short8;    // MFMA bf16 frag (4 VGPR)
typedef __attribute__((ext_vector_type(8)))  unsigned short ushort8;
typedef __attribute__((ext_vector_type(4)))  float  floatx4;
typedef __attribute__((ext_vector_type(16))) float  floatx16;  // 32x32 acc

#define WT3_ELEMS ((size_t)CCH * 36 * 512)   // 64c x (3n*12kt) x 64lane*8 ushorts
#define WS_NEED   (WT3_ELEMS * 2)            // 2.25 MB

__device__ __forceinline__ unsigned short f2bf(float f) {
    union { float f; unsigned u; } v; v.f = f;
    unsigned r = v.u + 0x7FFF + ((v.u >> 16) & 1);   // RNE
    return (unsigned short)(r >> 16);
}

// ===== k1w: pack W[c][o][t] into 32x32x16 MFMA B-fragment order =====
// Frag (c, n∈[0,3), kt∈[0,12)): lane l holds B[k=(l>>5)*8+j][col=n*32+(l&31)]
//   = W[c][kt*16 + (l>>5)*8 + j][n*32 + (l&31)], zero for o>=168.
__global__ __launch_bounds__(256)
void k1w(const float* __restrict__ W, unsigned short* __restrict__ Wt3)
{
    const int tid = threadIdx.x, l = tid & 63, w = tid >> 6;
    const int wid = blockIdx.x * 4 + w;          // 0..2303 = (c, n, kt)
    const int kt = wid % 12;
    const int n  = (wid / 12) % 3;
    const int c  = wid / 36;
    const int tm = l & 31, kh = l >> 5;
    const int t  = n * 32 + tm;
    ushort8 u;
    #pragma unroll
    for (int j = 0; j < 8; ++j) {
        int o = kt * 16 + kh * 8 + j;
        float val = (o < ORD) ? W[((size_t)c * ORD + o) * TT + t] : 0.f;
        u[j] = f2bf(val);
    }
    *(ushort8*)(Wt3 + (size_t)wid * 512 + l * 8) = u;
}

// ===== k2g: fused transpose + per-channel 32x32x16 bf16 MFMA GEMM =====
// Block = 4 c x 32 b x 96 t, 256 threads = 4 waves, wave = 1 channel.
// KEY CHANGE (R9): the wave's ENTIRE B operand (36 frags = 144 VGPR) is
// preloaded in one independent burst BEFORE X staging -> B-load latency hides
// under the staging phase; the MFMA burst touches only LDS + registers.
// Xs is stored in exact A-frag order -> conflict-free wave-uniform ds_read_b128.
// Grid: btile co-XCD mapping (R6, proven best for X/out locality).
__global__ __launch_bounds__(256, 2)
void k2g(const float* __restrict__ inp, const unsigned short* __restrict__ Wt3,
         const float* __restrict__ bias, float* __restrict__ out)
{
    __shared__ unsigned short XsU[4 * 12 * 64 * 8];   // 49152 B; Ys aliases it

    const int tid = threadIdx.x, l = tid & 63, wv = tid >> 6;   // wv = local channel
    const int tm = l & 31;                        // b-row (A/D) / t-col (B/D)
    const int btile = (blockIdx.x & 7) | ((blockIdx.x >> 7) << 3);   // 0..31
    const int cg    = (blockIdx.x >> 3) & 15;
    const int b0 = btile * 32, c0 = cg * 4;

    // ---- B preload: 36 independent b128 loads (wave-uniform base + lane*16B)
    const unsigned short* Wc = Wt3 + (size_t)(c0 + wv) * 36 * 512 + l * 8;
    short8 bfr[36];
    #pragma unroll
    for (int q = 0; q < 36; ++q)
        bfr[q] = *(const short8*)(Wc + (size_t)q * 512);

    // bias for this wave's channel (lane col = n*32 + tm)
    float bv[3];
    #pragma unroll
    for (int n = 0; n < 3; ++n)
        bv[n] = bias[(c0 + wv) * TT + n * 32 + tm];

    // ---- stage X in A-frag order: Xs[c][kt][kh*32+b][j] = bf16(inp[b0+b][OFF+o][c0+c])
    // 768 tasks (b 32, kchunk 24) over 256 threads; writes = 512-B runs, conflict-free.
    #pragma unroll
    for (int r = 0; r < 3; ++r) {
        int v = tid + r * 256;
        int b = v & 31, kchunk = v >> 5;          // kchunk 0..23
        int kt = kchunk >> 1, kh = kchunk & 1;
        floatx4 f[8];
        #pragma unroll
        for (int j = 0; j < 8; ++j) {
            int o = kchunk * 8 + j;
            floatx4 z = {0.f, 0.f, 0.f, 0.f};
            f[j] = (o < ORD)
                ? *(const floatx4*)(inp + ((size_t)(b0 + b) * SEQ + OFF + o) * CCH + c0)
                : z;
        }
        #pragma unroll
        for (int c = 0; c < 4; ++c) {
            ushort8 u;
            #pragma unroll
            for (int j = 0; j < 8; ++j) u[j] = f2bf(f[j][c]);
            *(ushort8*)(XsU + (size_t)(((c * 12 + kt) * 64 + kh * 32 + b)) * 8) = u;
        }
    }
    __syncthreads();

    // ---- MFMA burst: pure LDS + registers. 12 ds_read_b128 + 36 MFMA.
    floatx16 acc[3] = {};
    {
        const unsigned short* Xc = XsU + (size_t)(wv * 12) * 512 + l * 8;
        #pragma unroll
        for (int kt = 0; kt < 12; ++kt) {
            short8 a = *(const short8*)(Xc + kt * 512);
            acc[0] = __builtin_amdgcn_mfma_f32_32x32x16_bf16(a, bfr[0 * 12 + kt], acc[0], 0, 0, 0);
            acc[1] = __builtin_amdgcn_mfma_f32_32x32x16_bf16(a, bfr[1 * 12 + kt], acc[1], 0, 0, 0);
            acc[2] = __builtin_amdgcn_mfma_f32_32x32x16_bf16(a, bfr[2 * 12 + kt], acc[2], 0, 0, 0);
        }
    }
    __syncthreads();   // done reading Xs; reuse as Ys

    // ---- epilogue: acc -> Ys[b][c][t] (writes: lanes = consecutive t, conflict-free)
    // D layout (m74/m101): col = lane&31 (= t within n-tile), row b = (reg&3)+8*(reg>>2)+4*(lane>>5)
    float* Ys = (float*)XsU;                     // [32 b][4 c][96 t] = 49152 B
    {
        const int kh = l >> 5;
        #pragma unroll
        for (int n = 0; n < 3; ++n)
            #pragma unroll
            for (int rg = 0; rg < 16; ++rg) {
                int b = (rg & 3) + 8 * (rg >> 2) + 4 * kh;
                Ys[(b * 4 + wv) * TT + n * 32 + tm] = acc[n][rg] + bv[n];
            }
    }
    __syncthreads();

    // ---- store: float4 c-runs; the 16 cg-blocks of this btile share an XCD,
    // so the 16 partial 16-B writes per 256-B out line merge in its L2.
    #pragma unroll
    for (int r = 0; r < 12; ++r) {
        int v = tid + r * 256;                    // 0..3071
        int b = v / TT, t = v % TT;
        floatx4 y = { Ys[(b * 4 + 0) * TT + t], Ys[(b * 4 + 1) * TT + t],
                      Ys[(b * 4 + 2) * TT + t], Ys[(b * 4 + 3) * TT + t] };
        *(floatx4*)(out + ((size_t)(b0 + b) * TT + t) * CCH + c0) = y;
    }
}

// ===== fallback (round-2 kernel) if ws too small =====
#define MB  8
#define NT  16
#define KO  8
#define NCH (ORD/KO)
#define WSTRIDE 132
typedef __attribute__((address_space(3))) void* lds_ptr_t;
typedef const __attribute__((address_space(1))) void* gbl_ptr_t;

__global__ __launch_bounds__(256, 4)
void tcl_fallback(const float* __restrict__ inp, const float* __restrict__ W,
                  const float* __restrict__ bias, float* __restrict__ out)
{
    __shared__ float Xsf[MB * KO * CCH];
    __shared__ float Wsf[CCH * WSTRIDE];
    const int tid = threadIdx.x;
    const int c   = tid & 63;
    const int tg  = tid >> 6;
    const int bblk = blockIdx.x & 127;
    const int tblk = blockIdx.x >> 7;
    const int b0 = bblk * MB;
    const int t0 = tblk * NT;
    float acc[MB][4];
    #pragma unroll
    for (int bi = 0; bi < MB; ++bi)
        #pragma unroll
        for (int tj = 0; tj < 4; ++tj) acc[bi][tj] = 0.f;
    for (int ch = 0; ch < NCH; ++ch) {
        const int ob = ch * KO;
        #pragma unroll
        for (int k = 0; k < 4; ++k) {
            int v = tid + k * 256;
            int row = v >> 4, c4 = v & 15;
            int bi = row >> 3, oi = row & 7;
            const float* gp = inp + ((size_t)(b0 + bi) * SEQ + (OFF + ob + oi)) * CCH + c4 * 4;
            __builtin_amdgcn_global_load_lds((gbl_ptr_t)gp, (lds_ptr_t)(Xsf + v * 4), 16, 0, 0);
        }
        float4 wbuf[8];
        #pragma unroll
        for (int k = 0; k < 8; ++k) {
            int v = tid + k * 256;
            int cch = v >> 5, oi = (v >> 2) & 7, t4 = v & 3;
            wbuf[k] = *(const float4*)(W + (size_t)cch * (ORD * TT) + (size_t)(ob + oi) * TT + t0 + t4 * 4);
        }
        #pragma unroll
        for (int k = 0; k < 8; ++k) {
            int v = tid + k * 256;
            int cch = v >> 5, oi = (v >> 2) & 7, t4 = v & 3;
            *(float4*)(Wsf + cch * WSTRIDE + oi * NT + t4 * 4) = wbuf[k];
        }
        __syncthreads();
        #pragma unroll
        for (int oi = 0; oi < KO; ++oi) {
            const float4 wvv = *(const float4*)(Wsf + c * WSTRIDE + oi * NT + tg * 4);
            float xv[MB];
            #pragma unroll
            for (int bi = 0; bi < MB; ++bi) xv[bi] = Xsf[(bi * KO + oi) * CCH + c];
            #pragma unroll
            for (int bi = 0; bi < MB; ++bi) {
                acc[bi][0] += xv[bi] * wvv.x;
                acc[bi][1] += xv[bi] * wvv.y;
                acc[bi][2] += xv[bi] * wvv.z;
                acc[bi][3] += xv[bi] * wvv.w;
            }
        }
        __syncthreads();
    }
    const float4 bvv = *(const float4*)(bias + c * TT + t0 + tg * 4);
    #pragma unroll
    for (int bi = 0; bi < MB; ++bi) {
        size_t base = ((size_t)(b0 + bi) * TT + (t0 + tg * 4)) * CCH + c;
        out[base]           = acc[bi][0] + bvv.x;
        out[base + CCH]     = acc[bi][1] + bvv.y;
        out[base + 2 * CCH] = acc[bi][2] + bvv.z;
        out[base + 3 * CCH] = acc[bi][3] + bvv.w;
    }
}

extern "C" void kernel_launch(void* const* d_in, const int* in_sizes, int n_in,
                              void* d_out, int out_size, void* d_ws, size_t ws_size,
                              hipStream_t stream) {
    const float* inp  = (const float*)d_in[0];   // [1024][336][64]
    const float* W    = (const float*)d_in[1];   // [64][168][96]
    const float* bias = (const float*)d_in[2];   // [64][96]
    float* out = (float*)d_out;                  // [1024][96][64]

    if (ws_size >= WS_NEED) {
        unsigned short* Wt3 = (unsigned short*)d_ws;
        k1w<<<576, 256, 0, stream>>>(W, Wt3);
        k2g<<<512, 256, 0, stream>>>(inp, Wt3, bias, out);
    } else {
        tcl_fallback<<<768, 256, 0, stream>>>(inp, W, bias, out);
    }
}